// Round 2
// baseline (163.591 us; speedup 1.0000x reference)
//
#include <hip/hip_runtime.h>

// StochasticPool2d: x (B=32, C=64, H=224, W=224) f32.
// out[b,c,i,j] = max 2x2 window (zero-padded right/bottom) of x at
// (h_off[i]+2i, w_off[j]+2j)  -> (32,64,112,112)
//
// Wave-per-output-row: dense float4 staging of the two needed input rows
// into LDS, then per-lane 2x2 gather-max from LDS (2-way bank alias = free).

#define H 224
#define W 224
#define NH 112
#define NW 112
#define WPB 4  // waves per block

__global__ __launch_bounds__(256) void spool_kernel(
    const float* __restrict__ x,
    const int* __restrict__ h_off,
    const int* __restrict__ w_off,
    float* __restrict__ out) {
  // [wave][row 0/1][228 floats]; entries 224..227 are the zero pad.
  __shared__ float lds[WPB][2][228];

  const int lane = threadIdx.x & 63;
  const int wv = threadIdx.x >> 6;
  const int row_id = blockIdx.x * WPB + wv;  // global output-row index

  const int i = row_id % NH;
  const int plane = row_id / NH;  // b*C + c
  const int h = h_off[i] + 2 * i;  // in [0, 223]

  const float* p0 = x + ((size_t)plane * H + h) * W;
  const bool has1 = (h + 1 < H);

  const float4 z = make_float4(0.f, 0.f, 0.f, 0.f);
  if (lane < 56) {
    // 56 float4 per row, rows are 16B-aligned (W*4 = 896 B).
    float4 v0 = ((const float4*)p0)[lane];
    *(float4*)&lds[wv][0][lane * 4] = v0;
    float4 v1 = has1 ? ((const float4*)(p0 + W))[lane] : z;
    *(float4*)&lds[wv][1][lane * 4] = v1;
  } else if (lane == 56) {
    *(float4*)&lds[wv][0][224] = z;  // right pad (w+1 == 224)
  } else if (lane == 57) {
    *(float4*)&lds[wv][1][224] = z;
  }
  __syncthreads();

  const size_t obase = (size_t)row_id * NW;

  {
    const int j = lane;  // 0..63
    const int w = w_off[j] + 2 * j;
    float m = fmaxf(fmaxf(lds[wv][0][w], lds[wv][0][w + 1]),
                    fmaxf(lds[wv][1][w], lds[wv][1][w + 1]));
    out[obase + j] = m;
  }
  {
    const int j = lane + 64;  // 64..111 active
    if (j < NW) {
      const int w = w_off[j] + 2 * j;
      float m = fmaxf(fmaxf(lds[wv][0][w], lds[wv][0][w + 1]),
                      fmaxf(lds[wv][1][w], lds[wv][1][w + 1]));
      out[obase + j] = m;
    }
  }
}

extern "C" void kernel_launch(void* const* d_in, const int* in_sizes, int n_in,
                              void* d_out, int out_size, void* d_ws, size_t ws_size,
                              hipStream_t stream) {
  const float* x = (const float*)d_in[0];
  const int* h_off = (const int*)d_in[1];
  const int* w_off = (const int*)d_in[2];
  float* out = (float*)d_out;

  const int nrows = out_size / NW;           // 2048 * 112 = 229376
  const int grid = (nrows + WPB - 1) / WPB;  // 57344 (exact)
  spool_kernel<<<grid, 256, 0, stream>>>(x, h_off, w_off, out);
}

// Round 3
// 91.810 us; speedup vs baseline: 1.7818x; 1.7818x over previous
//
#include <hip/hip_runtime.h>

// StochasticPool2d: x (B=32, C=64, H=224, W=224) f32.
// out[b,c,i,j] = max 2x2 window (zero-padded right/bottom) of x at
// (h_off[i]+2i, w_off[j]+2j)  -> (32,64,112,112)
//
// 4 outputs per thread: all-float4 loads/stores, no LDS, no barriers,
// grid-stride loop over a capped grid. For outputs j=4*j4..4*j4+3 we need
// x[h][8*j4 .. 8*j4+8] and the row below: 6 float4 loads, 9 vertical maxes,
// then per-output horizontal max selected by the w_off bit.

#define H 224
#define W 224
#define NH 112
#define NW 112
#define J4 28  // NW/4 float4-groups per output row

__global__ __launch_bounds__(256) void spool_kernel(
    const float* __restrict__ x,
    const int* __restrict__ h_off,
    const int* __restrict__ w_off,
    float* __restrict__ out,
    int total4) {
  const int stride = gridDim.x * blockDim.x;
  for (int t = blockIdx.x * blockDim.x + threadIdx.x; t < total4; t += stride) {
    const int j4 = t % J4;
    const int r = t / J4;      // plane*NH + i
    const int i = r % NH;
    const int plane = r / NH;  // b*C + c

    const int h = h_off[i] + 2 * i;  // [0, 223]
    const bool has1 = (h + 1 < H);
    const bool hasR = (j4 != J4 - 1);

    const float4* p0 = (const float4*)(x + ((size_t)plane * H + h) * W) + 2 * j4;
    const float4* p1 = has1 ? p0 + (W / 4) : p0;  // safe in-bounds fallback

    // row h: floats [8j4 .. 8j4+7], plus [8j4+8] (use safe idx 1 when at edge)
    float4 a0 = p0[0];
    float4 a1 = p0[1];
    float4 a2 = p0[hasR ? 2 : 1];
    float4 b0 = p1[0];
    float4 b1 = p1[1];
    float4 b2 = p1[hasR ? 2 : 1];

    // vertical max v[m] = max(x[h][8j4+m], x[h+1][8j4+m] or pad 0)
    float v0 = fmaxf(a0.x, has1 ? b0.x : 0.f);
    float v1 = fmaxf(a0.y, has1 ? b0.y : 0.f);
    float v2 = fmaxf(a0.z, has1 ? b0.z : 0.f);
    float v3 = fmaxf(a0.w, has1 ? b0.w : 0.f);
    float v4 = fmaxf(a1.x, has1 ? b1.x : 0.f);
    float v5 = fmaxf(a1.y, has1 ? b1.y : 0.f);
    float v6 = fmaxf(a1.z, has1 ? b1.z : 0.f);
    float v7 = fmaxf(a1.w, has1 ? b1.w : 0.f);
    float v8 = fmaxf(hasR ? a2.x : 0.f, (has1 && hasR) ? b2.x : 0.f);

    // horizontal max, offset bit from w_off (0 or 1)
    const int4 wo = *((const int4*)w_off + j4);
    float o0 = wo.x ? fmaxf(v1, v2) : fmaxf(v0, v1);
    float o1 = wo.y ? fmaxf(v3, v4) : fmaxf(v2, v3);
    float o2 = wo.z ? fmaxf(v5, v6) : fmaxf(v4, v5);
    float o3 = wo.w ? fmaxf(v7, v8) : fmaxf(v6, v7);

    ((float4*)out)[t] = make_float4(o0, o1, o2, o3);  // == out[4t..4t+3]
  }
}

extern "C" void kernel_launch(void* const* d_in, const int* in_sizes, int n_in,
                              void* d_out, int out_size, void* d_ws, size_t ws_size,
                              hipStream_t stream) {
  const float* x = (const float*)d_in[0];
  const int* h_off = (const int*)d_in[1];
  const int* w_off = (const int*)d_in[2];
  float* out = (float*)d_out;

  const int total4 = out_size / 4;  // 6,422,528 float4 outputs
  const int block = 256;
  const int grid = 2048;  // grid-stride; ~8 blocks/CU resident, ~12 iters/thread
  spool_kernel<<<grid, block, 0, stream>>>(x, h_off, w_off, out, total4);
}